// Round 1
// baseline (139.033 us; speedup 1.0000x reference)
//
#include <hip/hip_runtime.h>

#define NW   10
#define DIM  1024
#define NBLK 4
#define TPB  256
#define SPT  (DIM / TPB)   // 4 states per thread

// P[s] = g0(g1(...g9(s))), gi = CNOT index map for pairs (0,1)...(8,9),(9,0)
__device__ __forceinline__ unsigned perm_idx(unsigned s) {
    unsigned b;
    b = s & 1u;            s ^= b << 9;     // pair (9,0): c bit pos 0, t bit pos 9
#pragma unroll
    for (int i = 8; i >= 0; --i) {          // pair (i, i+1): c pos 9-i, t pos 8-i
        b = (s >> (9 - i)) & 1u;
        s ^= b << (8 - i);
    }
    return s;
}

__global__ __launch_bounds__(TPB) void qsim_kernel(const float* __restrict__ x,
                                                   const float* __restrict__ params,
                                                   float* __restrict__ out) {
    __shared__ float re[DIM];
    __shared__ float im[DIM];
    __shared__ float sred[4 * NW];

    const int t = threadIdx.x;
    const int b = blockIdx.x;

    // init |0>
#pragma unroll
    for (int j = 0; j < SPT; ++j) {
        int s = t + j * TPB;
        re[s] = (s == 0) ? 1.0f : 0.0f;
        im[s] = 0.0f;
    }
    __syncthreads();

    auto rz = [&](const float* __restrict__ theta) {
        // preload thetas (uniform -> sgpr)
        float th[NW];
#pragma unroll
        for (int w = 0; w < NW; ++w) th[w] = theta[w];
#pragma unroll
        for (int j = 0; j < SPT; ++j) {
            int s = t + j * TPB;
            float dot = 0.f;
#pragma unroll
            for (int w = 0; w < NW; ++w) {
                float zv = ((s >> (9 - w)) & 1) ? -1.f : 1.f;
                dot += th[w] * zv;
            }
            float ang = -0.5f * dot;
            float sn, cs;
            __sincosf(ang, &sn, &cs);
            float r = re[s], i2 = im[s];
            re[s] = r * cs - i2 * sn;
            im[s] = r * sn + i2 * cs;
        }
        __syncthreads();
    };

    auto ry = [&](const float* __restrict__ theta) {
#pragma unroll
        for (int w = 0; w < NW; ++w) {
            const int bpos = 9 - w;
            const unsigned mask = 1u << bpos;
            const unsigned lowm = mask - 1u;
            float sn, cs;
            __sincosf(0.5f * theta[w], &sn, &cs);
#pragma unroll
            for (int j = 0; j < (DIM / 2) / TPB; ++j) {   // 2 pairs per thread
                unsigned p  = (unsigned)t + j * TPB;
                unsigned s0 = ((p & ~lowm) << 1) | (p & lowm);
                unsigned s1 = s0 | mask;
                float r0 = re[s0], i0 = im[s0];
                float r1 = re[s1], i1 = im[s1];
                re[s0] = cs * r0 - sn * r1;
                im[s0] = cs * i0 - sn * i1;
                re[s1] = sn * r0 + cs * r1;
                im[s1] = sn * i0 + cs * i1;
            }
            __syncthreads();
        }
    };

    auto perm = [&]() {
        float vr[SPT], vi[SPT];
#pragma unroll
        for (int j = 0; j < SPT; ++j) {
            unsigned s = (unsigned)t + j * TPB;
            unsigned q = perm_idx(s);
            vr[j] = re[q];
            vi[j] = im[q];
        }
        __syncthreads();
#pragma unroll
        for (int j = 0; j < SPT; ++j) {
            unsigned s = (unsigned)t + j * TPB;
            re[s] = vr[j];
            im[s] = vi[j];
        }
        __syncthreads();
    };

    for (int k = 0; k < NBLK; ++k) {
        const float* p = params + k * 6 * NW;
        rz(p + 0 * NW);
        ry(p + 1 * NW);
        rz(p + 2 * NW);
        perm();
        rz(p + 3 * NW);
        ry(p + 4 * NW);
        rz(p + 5 * NW);
        perm();
        if (k != NBLK - 1) {
            rz(x + b * NW);   // encoding phase, same form as RZ
        }
    }

    // out[b][w] = sum_s (re^2+im^2) * (1 - 2*bit_{9-w}(s))
    float acc[NW];
#pragma unroll
    for (int w = 0; w < NW; ++w) acc[w] = 0.f;
#pragma unroll
    for (int j = 0; j < SPT; ++j) {
        int s = t + j * TPB;
        float pr = re[s] * re[s] + im[s] * im[s];
#pragma unroll
        for (int w = 0; w < NW; ++w) {
            acc[w] += ((s >> (9 - w)) & 1) ? -pr : pr;
        }
    }
    // wave (64-lane) reduce, then cross-wave via LDS
#pragma unroll
    for (int w = 0; w < NW; ++w) {
#pragma unroll
        for (int off = 32; off > 0; off >>= 1)
            acc[w] += __shfl_down(acc[w], off, 64);
    }
    const int wave = t >> 6, lane = t & 63;
    if (lane == 0) {
#pragma unroll
        for (int w = 0; w < NW; ++w) sred[wave * NW + w] = acc[w];
    }
    __syncthreads();
    if (t < NW) {
        float v = sred[t] + sred[NW + t] + sred[2 * NW + t] + sred[3 * NW + t];
        out[b * NW + t] = v;
    }
}

extern "C" void kernel_launch(void* const* d_in, const int* in_sizes, int n_in,
                              void* d_out, int out_size, void* d_ws, size_t ws_size,
                              hipStream_t stream) {
    const float* x      = (const float*)d_in[0];   // (2048, 10)
    const float* params = (const float*)d_in[1];   // (4, 6, 10)
    float* out          = (float*)d_out;           // (1, 2048, 10)
    (void)in_sizes; (void)n_in; (void)out_size; (void)d_ws; (void)ws_size;
    qsim_kernel<<<2048, TPB, 0, stream>>>(x, params, out);
}

// Round 2
// 129.008 us; speedup vs baseline: 1.0777x; 1.0777x over previous
//
#include <hip/hip_runtime.h>

#define NW 10

// ---- Z-diagonal: state *= exp(i*ang(s)), ang(s) = -0.5*sum(th) + sum_{set bits} th_w
// lane bit j <-> s bit j+4 <-> wire 5-j ; reg bit j <-> s bit j <-> wire 9-j
__device__ __forceinline__ void diag_apply(float re[16], float im[16],
                                           const float th[NW], int lane) {
    float A = 0.f;
#pragma unroll
    for (int w = 0; w < NW; ++w) A += th[w];
    float hi = -0.5f * A;
#pragma unroll
    for (int j = 0; j < 6; ++j)
        hi += ((lane >> j) & 1) ? th[5 - j] : 0.0f;
    float lo[16];
    lo[0] = 0.f;
#pragma unroll
    for (int j = 0; j < 4; ++j) {
#pragma unroll
        for (int m = 0; m < 16; ++m) {
            if (m < (1 << j)) lo[m | (1 << j)] = lo[m] + th[9 - j];
        }
    }
#pragma unroll
    for (int r = 0; r < 16; ++r) {
        float ang = hi + lo[r];
        float sn, cs;
        __sincosf(ang, &sn, &cs);
        float a = re[r], b = im[r];
        re[r] = a * cs - b * sn;
        im[r] = a * sn + b * cs;
    }
}

// ---- RY sweep over all 10 wires. Wire w acts on bit k=9-w.
__device__ __forceinline__ void ry_apply(float re[16], float im[16],
                                         const float* __restrict__ th, int lane) {
#pragma unroll
    for (int w = 0; w < NW; ++w) {
        float sn, cs;
        __sincosf(0.5f * th[w], &sn, &cs);
        const int k = 9 - w;
        if (k < 4) {                       // register-bit wire: local pairs
            const int m = 1 << k;
#pragma unroll
            for (int r = 0; r < 16; ++r) {
                if (!(r & m)) {
                    const int r2 = r | m;
                    float a = re[r], b = re[r2];
                    re[r]  = cs * a - sn * b;
                    re[r2] = sn * a + cs * b;
                    float ai = im[r], bi = im[r2];
                    im[r]  = cs * ai - sn * bi;
                    im[r2] = sn * ai + cs * bi;
                }
            }
        } else {                           // lane-bit wire: shfl_xor exchange
            const int j = k - 4;
            const float ss = ((lane >> j) & 1) ? sn : -sn;
#pragma unroll
            for (int r = 0; r < 16; ++r) {
                float pre = __shfl_xor(re[r], 1 << j, 64);
                float pim = __shfl_xor(im[r], 1 << j, 64);
                re[r] = cs * re[r] + ss * pre;
                im[r] = cs * im[r] + ss * pim;
            }
        }
    }
}

// ---- Permutation new[s] = old[q(s)], q_k = s_k^s_{k+1} (k<=7), q8=s8^s9^s0, q9=s9^s0
// Stage 1: lane gather src_lane = lane ^ (lane>>1)
// Stage 2: reg gather src_reg = (r ^ ((r>>1)&7)) ^ (lane0<<3)
// Stage 3: odd regs pull from lane^32
__device__ __forceinline__ void perm_apply(float re[16], float im[16], int lane) {
    const int sl = lane ^ (lane >> 1);
#pragma unroll
    for (int r = 0; r < 16; ++r) {
        re[r] = __shfl(re[r], sl, 64);
        im[r] = __shfl(im[r], sl, 64);
    }
    const bool l0 = lane & 1;
    float tr[16], ti[16];
#pragma unroll
    for (int r = 0; r < 16; ++r) {
        const int idx = r ^ ((r >> 1) & 7);
        tr[r] = l0 ? re[idx ^ 8] : re[idx];
        ti[r] = l0 ? im[idx ^ 8] : im[idx];
    }
#pragma unroll
    for (int r = 0; r < 16; ++r) {
        if (r & 1) {
            re[r] = __shfl_xor(tr[r], 32, 64);
            im[r] = __shfl_xor(ti[r], 32, 64);
        } else {
            re[r] = tr[r];
            im[r] = ti[r];
        }
    }
}

__global__ __launch_bounds__(256) void qsim_kernel(const float* __restrict__ x,
                                                   const float* __restrict__ params,
                                                   float* __restrict__ out) {
    const int lane = threadIdx.x & 63;
    const int b = blockIdx.x * 4 + (threadIdx.x >> 6);

    float re[16], im[16];
#pragma unroll
    for (int r = 0; r < 16; ++r) { re[r] = 0.f; im[r] = 0.f; }
    if (lane == 0) re[0] = 1.f;   // |0...0>

    const float* xb = x + b * NW;

#pragma unroll 1
    for (int k = 0; k < 4; ++k) {
        const float* p = params + k * 6 * NW;
        float th[NW];
#pragma unroll
        for (int w = 0; w < NW; ++w)
            th[w] = p[w] + ((k > 0) ? xb[w] : 0.f);   // enc merged into next rz0
        diag_apply(re, im, th, lane);
        ry_apply(re, im, p + NW, lane);
#pragma unroll
        for (int w = 0; w < NW; ++w) th[w] = p[2 * NW + w];
        diag_apply(re, im, th, lane);
        perm_apply(re, im, lane);
#pragma unroll
        for (int w = 0; w < NW; ++w) th[w] = p[3 * NW + w];
        diag_apply(re, im, th, lane);
        ry_apply(re, im, p + 4 * NW, lane);
#pragma unroll
        for (int w = 0; w < NW; ++w) th[w] = p[5 * NW + w];
        diag_apply(re, im, th, lane);
        perm_apply(re, im, lane);
    }

    // out[b][w] = sum_s (re^2+im^2) * (1-2*bit_{9-w}(s))
    float pr[16];
#pragma unroll
    for (int r = 0; r < 16; ++r) pr[r] = re[r] * re[r] + im[r] * im[r];
    float S = 0.f;
#pragma unroll
    for (int r = 0; r < 16; ++r) S += pr[r];

    float acc[NW];
#pragma unroll
    for (int w = 0; w < 6; ++w)                 // lane-bit wires: sign(lane)*S
        acc[w] = ((lane >> (5 - w)) & 1) ? -S : S;
#pragma unroll
    for (int w = 6; w < NW; ++w) {              // reg-bit wires: local signed sum
        const int k = 9 - w;
        float t = 0.f;
#pragma unroll
        for (int r = 0; r < 16; ++r)
            t += ((r >> k) & 1) ? -pr[r] : pr[r];
        acc[w] = t;
    }
#pragma unroll
    for (int w = 0; w < NW; ++w) {
#pragma unroll
        for (int off = 32; off > 0; off >>= 1)
            acc[w] += __shfl_xor(acc[w], off, 64);
    }
    if (lane == 0) {
#pragma unroll
        for (int w = 0; w < NW; ++w) out[b * NW + w] = acc[w];
    }
}

extern "C" void kernel_launch(void* const* d_in, const int* in_sizes, int n_in,
                              void* d_out, int out_size, void* d_ws, size_t ws_size,
                              hipStream_t stream) {
    const float* x      = (const float*)d_in[0];   // (2048, 10)
    const float* params = (const float*)d_in[1];   // (4, 6, 10)
    float* out          = (float*)d_out;           // (1, 2048, 10)
    (void)in_sizes; (void)n_in; (void)out_size; (void)d_ws; (void)ws_size;
    qsim_kernel<<<512, 256, 0, stream>>>(x, params, out);
}

// Round 3
// 97.038 us; speedup vs baseline: 1.4328x; 1.3295x over previous
//
#include <hip/hip_runtime.h>

#define NW 10

// quad_perm DPP: xor1 = [1,0,3,2] = 0xB1, xor2 = [2,3,0,1] = 0x4E
template<int CTRL>
__device__ __forceinline__ float dpp_qperm(float v) {
    return __int_as_float(__builtin_amdgcn_mov_dpp(__float_as_int(v), CTRL, 0xF, 0xF, true));
}

// State layout: s9 = wave bit W, s[8:3] = lane bits, s[2:0] = reg index r.
// LDS layout:   addr(s) = lane | (r<<6) | (W<<9)  (stride-1 writes, 2-way gather)
__global__ __launch_bounds__(128) void qsim_kernel(const float* __restrict__ x,
                                                   const float* __restrict__ params,
                                                   float* __restrict__ out) {
    __shared__ float bre[1024];
    __shared__ float bim[1024];
    __shared__ float sred[2][NW];

    const int t     = threadIdx.x;
    const int W     = t >> 6;                 // s9
    const int lane  = t & 63;                 // s[8:3]
    const int b     = blockIdx.x;
    const int sbase = (W << 9) | (lane << 3); // state index of reg 0
    const int abase = lane | (W << 9);        // LDS addr of reg 0

    float re[8], im[8];
#pragma unroll
    for (int r = 0; r < 8; ++r) { re[r] = 0.f; im[r] = 0.f; }
    if (t == 0) re[0] = 1.f;                  // |0...0>

    const float* xb = x + b * NW;

    // ---- Z-diagonal: ang(s) = -0.5*sum(th) + sum_{set bits} th_w
    // reg bit j -> wire 9-j ; lane bit j -> wire 6-j ; wave bit -> wire 0
    auto diag = [&](const float th[NW]) {
        float A = 0.f;
#pragma unroll
        for (int w = 0; w < NW; ++w) A += th[w];
        float hi = -0.5f * A + (W ? th[0] : 0.f);
#pragma unroll
        for (int j = 0; j < 6; ++j)
            hi += ((lane >> j) & 1) ? th[6 - j] : 0.f;
        float lo[8];
        lo[0] = 0.f;           lo[1] = th[9];
        lo[2] = th[8];         lo[3] = th[8] + th[9];
        lo[4] = th[7];         lo[5] = th[7] + th[9];
        lo[6] = th[7] + th[8]; lo[7] = th[7] + th[8] + th[9];
#pragma unroll
        for (int r = 0; r < 8; ++r) {
            float sn, cs;
            __sincosf(hi + lo[r], &sn, &cs);
            float a = re[r], bb = im[r];
            re[r] = a * cs - bb * sn;
            im[r] = a * sn + bb * cs;
        }
    };

    // ---- RY sweep (all wires commute across different wires)
    auto ry = [&](const float* __restrict__ th) {
        // reg-bit wires: wire 9 (bit0), 8 (bit1), 7 (bit2)
#pragma unroll
        for (int kb = 0; kb < 3; ++kb) {
            float sn, cs;
            __sincosf(0.5f * th[9 - kb], &sn, &cs);
            const int m = 1 << kb;
#pragma unroll
            for (int r = 0; r < 8; ++r) {
                if (!(r & m)) {
                    const int r2 = r | m;
                    float a = re[r], bb = re[r2];
                    re[r]  = cs * a - sn * bb;
                    re[r2] = sn * a + cs * bb;
                    float ai = im[r], bi = im[r2];
                    im[r]  = cs * ai - sn * bi;
                    im[r2] = sn * ai + cs * bi;
                }
            }
        }
        // lane wire j=0 (wire 6): DPP xor1
        {
            float sn, cs; __sincosf(0.5f * th[6], &sn, &cs);
            const float ss = (lane & 1) ? sn : -sn;
#pragma unroll
            for (int r = 0; r < 8; ++r) {
                float pre = dpp_qperm<0xB1>(re[r]);
                float pim = dpp_qperm<0xB1>(im[r]);
                re[r] = cs * re[r] + ss * pre;
                im[r] = cs * im[r] + ss * pim;
            }
        }
        // lane wire j=1 (wire 5): DPP xor2
        {
            float sn, cs; __sincosf(0.5f * th[5], &sn, &cs);
            const float ss = (lane & 2) ? sn : -sn;
#pragma unroll
            for (int r = 0; r < 8; ++r) {
                float pre = dpp_qperm<0x4E>(re[r]);
                float pim = dpp_qperm<0x4E>(im[r]);
                re[r] = cs * re[r] + ss * pre;
                im[r] = cs * im[r] + ss * pim;
            }
        }
        // lane wires j=2..5 (wires 4..1): shfl_xor
#pragma unroll
        for (int j = 2; j < 6; ++j) {
            float sn, cs; __sincosf(0.5f * th[6 - j], &sn, &cs);
            const float ss = ((lane >> j) & 1) ? sn : -sn;
#pragma unroll
            for (int r = 0; r < 8; ++r) {
                float pre = __shfl_xor(re[r], 1 << j, 64);
                float pim = __shfl_xor(im[r], 1 << j, 64);
                re[r] = cs * re[r] + ss * pre;
                im[r] = cs * im[r] + ss * pim;
            }
        }
        // wave-bit wire 0 via LDS exchange
        {
            float sn, cs; __sincosf(0.5f * th[0], &sn, &cs);
            const float ss = W ? sn : -sn;
#pragma unroll
            for (int r = 0; r < 8; ++r) {
                bre[abase + (r << 6)] = re[r];
                bim[abase + (r << 6)] = im[r];
            }
            __syncthreads();
            const int pb = abase ^ 512;
#pragma unroll
            for (int r = 0; r < 8; ++r) {
                float pre = bre[pb + (r << 6)];
                float pim = bim[pb + (r << 6)];
                re[r] = cs * re[r] + ss * pre;
                im[r] = cs * im[r] + ss * pim;
            }
            __syncthreads();
        }
    };

    // ---- Permutation new[s] = old[q], q = s^(s>>1)^((s&1)*0x300)
    auto perm = [&]() {
#pragma unroll
        for (int r = 0; r < 8; ++r) {
            bre[abase + (r << 6)] = re[r];
            bim[abase + (r << 6)] = im[r];
        }
        __syncthreads();
#pragma unroll
        for (int r = 0; r < 8; ++r) {
            const int s = sbase + r;
            const int q = s ^ (s >> 1) ^ ((r & 1) * 0x300);
            const int a = ((q >> 3) & 63) | ((q & 7) << 6) | ((q >> 9) << 9);
            re[r] = bre[a];
            im[r] = bim[a];
        }
        __syncthreads();
    };

#pragma unroll 1
    for (int k = 0; k < 4; ++k) {
        const float* p = params + k * 6 * NW;
        float th[NW];
        if (k > 0) {                       // rz0 + enc of prev block (k==0: global phase, dropped)
#pragma unroll
            for (int w = 0; w < NW; ++w) th[w] = p[w] + xb[w];
            diag(th);
        }
        ry(p + NW);
#pragma unroll
        for (int w = 0; w < NW; ++w) th[w] = p[2 * NW + w];
        diag(th);
        perm();
#pragma unroll
        for (int w = 0; w < NW; ++w) th[w] = p[3 * NW + w];
        diag(th);
        ry(p + 4 * NW);
        if (k < 3) {                       // k==3: pure phase before |.|^2, dropped
#pragma unroll
            for (int w = 0; w < NW; ++w) th[w] = p[5 * NW + w];
            diag(th);
        }
        perm();
    }

    // ---- out[b][w] = sum_s (re^2+im^2) * (1-2*bit_{9-w}(s))
    float pr[8];
#pragma unroll
    for (int r = 0; r < 8; ++r) pr[r] = re[r] * re[r] + im[r] * im[r];
    float S = 0.f;
#pragma unroll
    for (int r = 0; r < 8; ++r) S += pr[r];

    float acc[NW];
    acc[0] = W ? -S : S;                       // wave bit
#pragma unroll
    for (int w = 1; w <= 6; ++w) {             // lane bit j = 6-w
        const int j = 6 - w;
        acc[w] = ((lane >> j) & 1) ? -S : S;
    }
#pragma unroll
    for (int w = 7; w < NW; ++w) {             // reg bit 9-w
        const int kb = 9 - w;
        float tt = 0.f;
#pragma unroll
        for (int r = 0; r < 8; ++r)
            tt += ((r >> kb) & 1) ? -pr[r] : pr[r];
        acc[w] = tt;
    }
#pragma unroll
    for (int w = 0; w < NW; ++w) {
        float a = acc[w];
        a += dpp_qperm<0xB1>(a);
        a += dpp_qperm<0x4E>(a);
        a += __shfl_xor(a, 4, 64);
        a += __shfl_xor(a, 8, 64);
        a += __shfl_xor(a, 16, 64);
        a += __shfl_xor(a, 32, 64);
        acc[w] = a;
    }
    if (lane == 0) {
#pragma unroll
        for (int w = 0; w < NW; ++w) sred[W][w] = acc[w];
    }
    __syncthreads();
    if (t < NW) out[b * NW + t] = sred[0][t] + sred[1][t];
}

extern "C" void kernel_launch(void* const* d_in, const int* in_sizes, int n_in,
                              void* d_out, int out_size, void* d_ws, size_t ws_size,
                              hipStream_t stream) {
    const float* x      = (const float*)d_in[0];   // (2048, 10)
    const float* params = (const float*)d_in[1];   // (4, 6, 10)
    float* out          = (float*)d_out;           // (1, 2048, 10)
    (void)in_sizes; (void)n_in; (void)out_size; (void)d_ws; (void)ws_size;
    qsim_kernel<<<2048, 128, 0, stream>>>(x, params, out);
}

// Round 4
// 86.315 us; speedup vs baseline: 1.6108x; 1.1242x over previous
//
#include <hip/hip_runtime.h>

#define NW 10

// DPP helpers: quad_perm xor1=0xB1, xor2=0x4E; row_ror:8 (=xor8 within 16) = 0x128
template<int CTRL>
__device__ __forceinline__ float fdpp(float v) {
    return __int_as_float(__builtin_amdgcn_mov_dpp(__float_as_int(v), CTRL, 0xF, 0xF, true));
}
// ds_swizzle BitMode: offset = xor<<10 | 0x1F. xor4=0x101F, xor16=0x401F (within 32 lanes)
template<int PAT>
__device__ __forceinline__ float fswz(float v) {
    return __int_as_float(__builtin_amdgcn_ds_swizzle(__float_as_int(v), PAT));
}

// ---------------- precompute: 14 diag phase tables + 80 RY (cos,sin) pairs ----------------
// table d: d<3 -> rz0 of block d+1 ; d<7 -> rz2 of block d-3 ; d<11 -> rz3 of block d-7 ;
//          else rz5 of block d-11.   entry j: idx j = lane | W<<6 | r<<7 for s = W<<9|lane<<3|r
__global__ void precompute_kernel(const float* __restrict__ params, float2* __restrict__ tab) {
    const int d = blockIdx.x;
    const int j = threadIdx.x;
    if (d < 14) {
        int k, row;
        if (d < 3)       { k = d + 1;  row = 0; }
        else if (d < 7)  { k = d - 3;  row = 2; }
        else if (d < 11) { k = d - 7;  row = 3; }
        else             { k = d - 11; row = 5; }
        const float* th = params + (k * 6 + row) * NW;
        const int s = (((j >> 6) & 1) << 9) | ((j & 63) << 3) | (j >> 7);
        float ang = 0.f;
#pragma unroll
        for (int w = 0; w < NW; ++w)
            ang += th[w] * (((s >> (9 - w)) & 1) ? 0.5f : -0.5f);
        float sn, cs;
        __sincosf(ang, &sn, &cs);
        tab[d * 1024 + j] = make_float2(cs, sn);
    } else if (j < 80) {
        const int ry = j / NW, w = j % NW;
        const int k = ry >> 1, i = ry & 1;
        const float* th = params + (k * 6 + (i ? 4 : 1)) * NW;
        float sn, cs;
        __sincosf(0.5f * th[w], &sn, &cs);
        tab[14 * 1024 + j] = make_float2(cs, sn);
    }
}

// ---------------- main kernel ----------------
// s9 = wave bit W, s[8:3] = lane, s[2:0] = reg r.  LDS float2 element e(s)=lane|W<<6|r<<7.
__global__ __launch_bounds__(128, 4) void qsim_kernel(const float* __restrict__ x,
                                                      const float2* __restrict__ tab,
                                                      float* __restrict__ out) {
    __shared__ float2 buf[2][1024];
    __shared__ float sred[2][NW];

    const int t     = threadIdx.x;
    const int W     = t >> 6;
    const int lane  = t & 63;
    const int b     = blockIdx.x;
    const int ebase = lane | (W << 6);
    const float2* ry_tab = tab + 14 * 1024;

    float re[8], im[8];
#pragma unroll
    for (int r = 0; r < 8; ++r) { re[r] = 0.f; im[r] = 0.f; }
    if (t == 0) re[0] = 1.f;

    // perm gather element indices (constant per thread)
    int geidx[8];
#pragma unroll
    for (int r = 0; r < 8; ++r) {
        const int s = (W << 9) | (lane << 3) | r;
        const int q = s ^ (s >> 1) ^ ((r & 1) * 0x300);
        geidx[r] = ((q >> 3) & 63) | (((q >> 9) & 1) << 6) | ((q & 7) << 7);
    }

    // x-phase e^{iA_x(s)} computed once, reused for the 3 encoding diagonals
    const float* xb = x + b * NW;
    float xr[8], xi[8];
    {
        float xv[NW];
#pragma unroll
        for (int w = 0; w < NW; ++w) xv[w] = xb[w];
        float A = 0.f;
#pragma unroll
        for (int w = 0; w < NW; ++w) A += xv[w];
        float hi = -0.5f * A + (W ? xv[0] : 0.f);
#pragma unroll
        for (int j = 0; j < 6; ++j)
            hi += ((lane >> j) & 1) ? xv[6 - j] : 0.f;
        float lo[8];
        lo[0] = 0.f;             lo[1] = xv[9];
        lo[2] = xv[8];           lo[3] = xv[8] + xv[9];
        lo[4] = xv[7];           lo[5] = xv[7] + xv[9];
        lo[6] = xv[7] + xv[8];   lo[7] = xv[7] + xv[8] + xv[9];
#pragma unroll
        for (int r = 0; r < 8; ++r)
            __sincosf(hi + lo[r], &xi[r], &xr[r]);
    }

    int bs = 0;

    auto tdiag = [&](int d) {
        const float2* tb = tab + (d << 10) + ebase;
#pragma unroll
        for (int r = 0; r < 8; ++r) {
            const float2 p = tb[r << 7];
            const float a = re[r], bb = im[r];
            re[r] = a * p.x - bb * p.y;
            im[r] = a * p.y + bb * p.x;
        }
    };
    auto txdiag = [&](int d) {   // table phase * x phase * amplitude
        const float2* tb = tab + (d << 10) + ebase;
#pragma unroll
        for (int r = 0; r < 8; ++r) {
            const float2 p = tb[r << 7];
            const float cx = p.x * xr[r] - p.y * xi[r];
            const float sx = p.x * xi[r] + p.y * xr[r];
            const float a = re[r], bb = im[r];
            re[r] = a * cx - bb * sx;
            im[r] = a * sx + bb * cx;
        }
    };

    auto ry = [&](int ridx) {
        const float2* rt = ry_tab + ridx * NW;
        // reg-bit wires: wire 9 (bit0), 8 (bit1), 7 (bit2)
#pragma unroll
        for (int kb = 0; kb < 3; ++kb) {
            const float2 cw = rt[9 - kb];
            const int m = 1 << kb;
#pragma unroll
            for (int r = 0; r < 8; ++r) {
                if (!(r & m)) {
                    const int r2 = r | m;
                    float a = re[r], bb = re[r2];
                    re[r]  = cw.x * a - cw.y * bb;
                    re[r2] = cw.y * a + cw.x * bb;
                    float ai = im[r], bi = im[r2];
                    im[r]  = cw.x * ai - cw.y * bi;
                    im[r2] = cw.y * ai + cw.x * bi;
                }
            }
        }
        // wire 6: xor1 (DPP quad)
        {
            const float2 cw = rt[6];
            const float ss = (lane & 1) ? cw.y : -cw.y;
#pragma unroll
            for (int r = 0; r < 8; ++r) {
                float pre = fdpp<0xB1>(re[r]);
                float pim = fdpp<0xB1>(im[r]);
                re[r] = cw.x * re[r] + ss * pre;
                im[r] = cw.x * im[r] + ss * pim;
            }
        }
        // wire 5: xor2 (DPP quad)
        {
            const float2 cw = rt[5];
            const float ss = (lane & 2) ? cw.y : -cw.y;
#pragma unroll
            for (int r = 0; r < 8; ++r) {
                float pre = fdpp<0x4E>(re[r]);
                float pim = fdpp<0x4E>(im[r]);
                re[r] = cw.x * re[r] + ss * pre;
                im[r] = cw.x * im[r] + ss * pim;
            }
        }
        // wire 4: xor4 (ds_swizzle)
        {
            const float2 cw = rt[4];
            const float ss = (lane & 4) ? cw.y : -cw.y;
#pragma unroll
            for (int r = 0; r < 8; ++r) {
                float pre = fswz<0x101F>(re[r]);
                float pim = fswz<0x101F>(im[r]);
                re[r] = cw.x * re[r] + ss * pre;
                im[r] = cw.x * im[r] + ss * pim;
            }
        }
        // wire 3: xor8 (DPP row_ror:8)
        {
            const float2 cw = rt[3];
            const float ss = (lane & 8) ? cw.y : -cw.y;
#pragma unroll
            for (int r = 0; r < 8; ++r) {
                float pre = fdpp<0x128>(re[r]);
                float pim = fdpp<0x128>(im[r]);
                re[r] = cw.x * re[r] + ss * pre;
                im[r] = cw.x * im[r] + ss * pim;
            }
        }
        // wire 2: xor16 (ds_swizzle)
        {
            const float2 cw = rt[2];
            const float ss = (lane & 16) ? cw.y : -cw.y;
#pragma unroll
            for (int r = 0; r < 8; ++r) {
                float pre = fswz<0x401F>(re[r]);
                float pim = fswz<0x401F>(im[r]);
                re[r] = cw.x * re[r] + ss * pre;
                im[r] = cw.x * im[r] + ss * pim;
            }
        }
        // wire 1: xor32 (bpermute)
        {
            const float2 cw = rt[1];
            const float ss = (lane & 32) ? cw.y : -cw.y;
#pragma unroll
            for (int r = 0; r < 8; ++r) {
                float pre = __shfl_xor(re[r], 32, 64);
                float pim = __shfl_xor(im[r], 32, 64);
                re[r] = cw.x * re[r] + ss * pre;
                im[r] = cw.x * im[r] + ss * pim;
            }
        }
        // wire 0: wave-bit exchange via LDS (double-buffered, 1 barrier)
        {
            const float2 cw = rt[0];
            float2* B = buf[bs]; bs ^= 1;
#pragma unroll
            for (int r = 0; r < 8; ++r)
                B[ebase + (r << 7)] = make_float2(re[r], im[r]);
            __syncthreads();
            const float ss = W ? cw.y : -cw.y;
            const int pb = ebase ^ 64;
#pragma unroll
            for (int r = 0; r < 8; ++r) {
                const float2 p = B[pb + (r << 7)];
                re[r] = cw.x * re[r] + ss * p.x;
                im[r] = cw.x * im[r] + ss * p.y;
            }
        }
    };

    auto perm = [&]() {
        float2* B = buf[bs]; bs ^= 1;
#pragma unroll
        for (int r = 0; r < 8; ++r)
            B[ebase + (r << 7)] = make_float2(re[r], im[r]);
        __syncthreads();
#pragma unroll
        for (int r = 0; r < 8; ++r) {
            const float2 p = B[geidx[r]];
            re[r] = p.x;
            im[r] = p.y;
        }
    };

#pragma unroll 1
    for (int k = 0; k < 4; ++k) {
        if (k > 0) txdiag(k - 1);       // enc(prev) + rz0(k); k=0 rz0 is global phase
        ry(2 * k);
        tdiag(3 + k);                   // rz2
        perm();
        tdiag(7 + k);                   // rz3
        ry(2 * k + 1);
        if (k < 3) tdiag(11 + k);       // rz5; k=3: pure phase before |.|^2
        perm();
    }

    // out[b][w] = sum_s (re^2+im^2) * (1-2*bit_{9-w}(s))
    float pr[8];
#pragma unroll
    for (int r = 0; r < 8; ++r) pr[r] = re[r] * re[r] + im[r] * im[r];
    float S = 0.f;
#pragma unroll
    for (int r = 0; r < 8; ++r) S += pr[r];

    float acc[NW];
    acc[0] = W ? -S : S;
#pragma unroll
    for (int w = 1; w <= 6; ++w) {
        const int j = 6 - w;
        acc[w] = ((lane >> j) & 1) ? -S : S;
    }
#pragma unroll
    for (int w = 7; w < NW; ++w) {
        const int kb = 9 - w;
        float tt = 0.f;
#pragma unroll
        for (int r = 0; r < 8; ++r)
            tt += ((r >> kb) & 1) ? -pr[r] : pr[r];
        acc[w] = tt;
    }
#pragma unroll
    for (int w = 0; w < NW; ++w) {
        float a = acc[w];
        a += fdpp<0xB1>(a);
        a += fdpp<0x4E>(a);
        a += fswz<0x101F>(a);
        a += fdpp<0x128>(a);
        a += fswz<0x401F>(a);
        a += __shfl_xor(a, 32, 64);
        acc[w] = a;
    }
    if (lane == 0) {
#pragma unroll
        for (int w = 0; w < NW; ++w) sred[W][w] = acc[w];
    }
    __syncthreads();
    if (t < NW) out[b * NW + t] = sred[0][t] + sred[1][t];
}

extern "C" void kernel_launch(void* const* d_in, const int* in_sizes, int n_in,
                              void* d_out, int out_size, void* d_ws, size_t ws_size,
                              hipStream_t stream) {
    const float* x      = (const float*)d_in[0];   // (2048, 10)
    const float* params = (const float*)d_in[1];   // (4, 6, 10)
    float* out          = (float*)d_out;           // (1, 2048, 10)
    float2* tab         = (float2*)d_ws;           // 14*1024 + 80 float2 = 115 KB
    (void)in_sizes; (void)n_in; (void)out_size; (void)ws_size;
    precompute_kernel<<<15, 1024, 0, stream>>>(params, tab);
    qsim_kernel<<<2048, 128, 0, stream>>>(x, tab, out);
}